// Round 5
// baseline (339.729 us; speedup 1.0000x reference)
//
#include <hip/hip_runtime.h>

// RNN: h_t = tanh(x_t * W_ih^T + b_ih + h_{t-1} W_hh^T + b_hh), out = h_T W_fc^T + b_fc
// B=8192, T=784, I=1, H=30 (pad 32), C=10. fp32.
//
// R7: DPP-count reduction. R6 proved weights are register-resident (VGPR 88)
// yet dur didn't move => the binder is the MAC stream itself. Measured VALU
// occupancy is ~2x the 2clk/op model across R4/R6; the un-benchmarked class
// is DPP ops => theory: DPP-modified VALU runs ~half rate (~4clk) on CDNA4.
// Fix: per k-pair, 2 raw v_mov_b32_dpp broadcasts into a fixed v-pair
// (v40..v43, clobbered) + 2 v_pk_fma_f32 (packed fp32, full-rate VOP3P).
// Same 60-instr/step floor, DPP ops 60 -> 30. Movs are hoisted 4 instrs
// ahead of their consuming pk_fma (dep-latency cover); acc chains alternate
// %0/%1 for >=4clk spacing. No tied-old copies (all lanes written).
// Keeps: volatile weight pins, amdgpu_waves_per_eu(2,2).

#define BB 8192
#define TT 784
#define HH 30
#define CC 10
#define NB 16      // batches per 256-thread block (4 per wave)
#define LSTR 36    // LDS row stride (floats) for the final FC exchange

typedef __attribute__((ext_vector_type(2))) float f32x2;

// Two k-groups fused: broadcast h0/h1 from lanes k0,k1 of the 16-lane DPP row
// into v[40:41] / v[42:43], then 4 packed FMAs (8 scalar MACs).
// acc0 = rows i0 (even/odd col partials), acc1 = rows i0+1.
#define PK2(k0, k1)                                                          \
    asm volatile(                                                            \
        "v_mov_b32_dpp v40, %2 row_newbcast:" #k0 " row_mask:0xf bank_mask:0xf\n\t" \
        "v_mov_b32_dpp v41, %3 row_newbcast:" #k0 " row_mask:0xf bank_mask:0xf\n\t" \
        "v_mov_b32_dpp v42, %2 row_newbcast:" #k1 " row_mask:0xf bank_mask:0xf\n\t" \
        "v_mov_b32_dpp v43, %3 row_newbcast:" #k1 " row_mask:0xf bank_mask:0xf\n\t" \
        "v_pk_fma_f32 %0, %4, v[40:41], %0\n\t"                              \
        "v_pk_fma_f32 %1, %5, v[40:41], %1\n\t"                              \
        "v_pk_fma_f32 %0, %6, v[42:43], %0\n\t"                              \
        "v_pk_fma_f32 %1, %7, v[42:43], %1"                                  \
        : "+v"(acc0), "+v"(acc1)                                             \
        : "v"(h0), "v"(h1), "v"(w0p[k0]), "v"(w1p[k0]),                      \
          "v"(w0p[k1]), "v"(w1p[k1])                                         \
        : "v40", "v41", "v42", "v43")

// last (odd) k-group alone
#define PK1(k0)                                                              \
    asm volatile(                                                            \
        "v_mov_b32_dpp v40, %2 row_newbcast:" #k0 " row_mask:0xf bank_mask:0xf\n\t" \
        "v_mov_b32_dpp v41, %3 row_newbcast:" #k0 " row_mask:0xf bank_mask:0xf\n\t" \
        "s_nop 0\n\t"                                                        \
        "v_pk_fma_f32 %0, %4, v[40:41], %0\n\t"                              \
        "v_pk_fma_f32 %1, %5, v[40:41], %1"                                  \
        : "+v"(acc0), "+v"(acc1)                                             \
        : "v"(h0), "v"(h1), "v"(w0p[k0]), "v"(w1p[k0])                       \
        : "v40", "v41")

__global__ __launch_bounds__(256)
__attribute__((amdgpu_waves_per_eu(2, 2)))
void rnn_scan_kernel(const float* __restrict__ x,
                     const float* __restrict__ W_ih,
                     const float* __restrict__ W_hh,
                     const float* __restrict__ b_ih,
                     const float* __restrict__ b_hh,
                     const float* __restrict__ W_fc,
                     const float* __restrict__ b_fc,
                     float* __restrict__ out) {
    __shared__ float hbuf[NB * LSTR];

    const int tid = threadIdx.x;
    const int bl  = tid >> 4;          // local batch 0..15 (4 per wave)
    const int r   = tid & 15;          // lane within the 16-lane DPP row
    const int i0  = r * 2;             // owned rows i0, i0+1
    const int b   = blockIdx.x * NB + bl;

    // --- per-thread weights: rows i0, i0+1, as 15 column-pairs (cols 0..29;
    // cols 30,31 are structural zeros and k=15 is skipped entirely) ---
    f32x2 w0p[15], w1p[15];
    const bool v0 = (i0 < HH), v1 = (i0 + 1 < HH);
#pragma unroll
    for (int k = 0; k < 15; ++k) {
        const int c0 = 2 * k, c1 = 2 * k + 1;
        w0p[k].x = v0 ? W_hh[i0 * HH + c0] : 0.0f;
        w0p[k].y = v0 ? W_hh[i0 * HH + c1] : 0.0f;
        w1p[k].x = v1 ? W_hh[(i0 + 1) * HH + c0] : 0.0f;
        w1p[k].y = v1 ? W_hh[(i0 + 1) * HH + c1] : 0.0f;
    }
    float bias0 = v0 ? (b_ih[i0] + b_hh[i0]) : 0.0f;
    float bias1 = v1 ? (b_ih[i0 + 1] + b_hh[i0 + 1]) : 0.0f;
    float wih0  = v0 ? W_ih[i0] : 0.0f;
    float wih1  = v1 ? W_ih[i0 + 1] : 0.0f;

    // volatile pins: cannot be sunk/duplicated; weights stay VGPR-resident
    // for the whole scan (verified by R6: VGPR_Count 44 -> 88).
#pragma unroll
    for (int k = 0; k < 15; ++k) {
        asm volatile("" : "+v"(w0p[k]));
        asm volatile("" : "+v"(w1p[k]));
    }
    asm volatile("" : "+v"(bias0));
    asm volatile("" : "+v"(bias1));
    asm volatile("" : "+v"(wih0));
    asm volatile("" : "+v"(wih1));

    // h in registers: lane r holds h[2r], h[2r+1]. Lane 15 (rows 30,31) is
    // never read (k=15 skipped); its own h stays exactly 0.
    float h0 = 0.0f, h1 = 0.0f;

    const float* xb = x + (size_t)b * TT;
    float4 xq = *(const float4*)(xb);

    for (int q = 0; q < TT / 4; ++q) {
        float4 nxt = (q + 1 < TT / 4) ? *(const float4*)(xb + (q + 1) * 4)
                                      : make_float4(0.f, 0.f, 0.f, 0.f);
#pragma unroll
        for (int u = 0; u < 4; ++u) {
            const float xt = (u == 0) ? xq.x : (u == 1) ? xq.y
                           : (u == 2) ? xq.z : xq.w;
            // row partials live as (even-col, odd-col) packed pairs
            f32x2 acc0 = {fmaf(xt, wih0, bias0), 0.0f};
            f32x2 acc1 = {fmaf(xt, wih1, bias1), 0.0f};
            // cover VALU-write(h0/h1) -> DPP-read hazard (2 wait states)
            asm volatile("s_nop 1");
            PK2( 0,  1); PK2( 2,  3); PK2( 4,  5); PK2( 6,  7);
            PK2( 8,  9); PK2(10, 11); PK2(12, 13); PK1(14);
            const float acc0s = acc0.x + acc0.y;
            const float acc1s = acc1.x + acc1.y;
            // tanh(a) = 1 - 2/(e^{2a}+1)   (identical numerics to R2..R6)
            h0 = 1.0f - 2.0f * __builtin_amdgcn_rcpf(__expf(2.0f * acc0s) + 1.0f);
            h1 = 1.0f - 2.0f * __builtin_amdgcn_rcpf(__expf(2.0f * acc1s) + 1.0f);
        }
        xq = nxt;
    }

    // --- FC head: park final h in LDS once; threads r<10 each do one output.
    float* hp = &hbuf[bl * LSTR];
    *(float2*)&hp[i0] = make_float2(h0, h1);
    __builtin_amdgcn_wave_barrier();

    if (r < CC) {
        const int c = r;
        float acc = b_fc[c];
#pragma unroll
        for (int j = 0; j < HH; ++j)
            acc += W_fc[c * HH + j] * hp[j];
        out[(size_t)b * CC + c] = acc;
    }
}

extern "C" void kernel_launch(void* const* d_in, const int* in_sizes, int n_in,
                              void* d_out, int out_size, void* d_ws, size_t ws_size,
                              hipStream_t stream) {
    const float* x    = (const float*)d_in[0];
    const float* W_ih = (const float*)d_in[1];
    const float* W_hh = (const float*)d_in[2];
    const float* b_ih = (const float*)d_in[3];
    const float* b_hh = (const float*)d_in[4];
    const float* W_fc = (const float*)d_in[5];
    const float* b_fc = (const float*)d_in[6];

    hipLaunchKernelGGL(rnn_scan_kernel,
                       dim3(BB / NB), dim3(NB * 16), 0, stream,
                       x, W_ih, W_hh, b_ih, b_hh, W_fc, b_fc,
                       (float*)d_out);
}